// Round 3
// baseline (26.847 us; speedup 1.0000x reference)
//
#include <hip/hip_runtime.h>
#include <math.h>

typedef _Float16 f16x8 __attribute__((ext_vector_type(8)));
typedef float    f32x4 __attribute__((ext_vector_type(4)));

#define SCRW 132           // 128 + 4 pad
#define G_IMG 8            // images per wave in interp kernel

typedef __attribute__((address_space(3))) void lds_void;
typedef const __attribute__((address_space(1))) void glb_void;

__device__ __forceinline__ f32x4 mfma16(f16x8 a, f16x8 b, f32x4 c) {
  return __builtin_amdgcn_mfma_f32_16x16x32_f16(a, b, c, 0, 0, 0);
}

// 8 contiguous f32 -> hi/lo f16 fragments (hi+lo ~= exact)
__device__ __forceinline__ void splitP(const float* p, f16x8& hi, f16x8& lo) {
  const f32x4* q = (const f32x4*)p;
  f32x4 a0 = q[0], a1 = q[1];
#pragma unroll
  for (int j = 0; j < 4; ++j) {
    _Float16 h0 = (_Float16)a0[j], h1 = (_Float16)a1[j];
    hi[j] = h0; hi[j + 4] = h1;
    lo[j]     = (_Float16)(a0[j] - (float)h0);
    lo[j + 4] = (_Float16)(a1[j] - (float)h1);
  }
}

// 8 strided f32 -> hi/lo f16 fragments
__device__ __forceinline__ void splitS(const float* p, int stride, f16x8& hi, f16x8& lo) {
#pragma unroll
  for (int j = 0; j < 8; ++j) {
    float x = p[j * stride];
    _Float16 h = (_Float16)x;
    hi[j] = h;
    lo[j] = (_Float16)(x - (float)h);
  }
}

// 8 contiguous f32 -> single-f16 B fragment (classifier weights)
__device__ __forceinline__ f16x8 bfrag8(const float* p) {
  const f32x4* q = (const f32x4*)p;
  f32x4 w0 = q[0], w1 = q[1];
  f16x8 b;
#pragma unroll
  for (int j = 0; j < 4; ++j) { b[j] = (_Float16)w0[j]; b[j + 4] = (_Float16)w1[j]; }
  return b;
}

// ================= Kernel 1: image streaming + linear interp taps =================
// wave = one image at a time, G_IMG images per wave, LDS double-buffered.
// lanes 0-31: sensory taps (flat image); lanes 32-63: topdown taps (transposed).
__global__ __launch_bounds__(256) void interp_k(const float* __restrict__ img,
                                                float* __restrict__ sensW,
                                                float* __restrict__ tdW) {
  __shared__ float buf[4][2][800];
  const int tid = threadIdx.x, wv = tid >> 6, l = tid & 63;
  const int u = l & 31, half = l >> 5;
  const int img0 = (blockIdx.x * 4 + wv) * G_IMG;

  const float pos = 24.5f * (float)u + 11.75f;
  const int lo = (int)pos;
  const float w = pos - (float)lo;
  const int ta = (lo % 28) * 28 + lo / 28;
  const int tb = ((lo + 1) % 28) * 28 + (lo + 1) / 28;
  const int p0 = half ? ta : lo;
  const int p1 = half ? tb : (lo + 1);
  const float scale = half ? 40.0f : 80.0f;
  float* outp = half ? tdW : sensW;

  // prologue: image 0 -> buf[wv][0]
  {
    const float* src = img + (size_t)img0 * 784;
    float* dst = &buf[wv][0][0];
#pragma unroll
    for (int j = 0; j < 3; ++j)
      __builtin_amdgcn_global_load_lds((glb_void*)(src + j * 256 + l * 4),
                                       (lds_void*)(dst + j * 256), 16, 0, 0);
    if (l < 4)
      __builtin_amdgcn_global_load_lds((glb_void*)(src + 768 + l * 4),
                                       (lds_void*)(dst + 768), 16, 0, 0);
  }

  float v[G_IMG];
#pragma unroll
  for (int i = 0; i < G_IMG; ++i) {
    if (i + 1 < G_IMG) {   // prefetch next image into the other buffer half
      const float* src = img + (size_t)(img0 + i + 1) * 784;
      float* dst = &buf[wv][(i + 1) & 1][0];
#pragma unroll
      for (int j = 0; j < 3; ++j)
        __builtin_amdgcn_global_load_lds((glb_void*)(src + j * 256 + l * 4),
                                         (lds_void*)(dst + j * 256), 16, 0, 0);
      if (l < 4)
        __builtin_amdgcn_global_load_lds((glb_void*)(src + 768 + l * 4),
                                         (lds_void*)(dst + 768), 16, 0, 0);
      asm volatile("s_waitcnt vmcnt(4)" ::: "memory");   // wait image i (4 newest = i+1)
    } else {
      asm volatile("s_waitcnt vmcnt(0)" ::: "memory");
    }
    __builtin_amdgcn_sched_barrier(0);
    const float* b = &buf[wv][i & 1][0];
    float v0 = b[p0], v1 = b[p1];
    v[i] = (v0 * (1.0f - w) + v1 * w) * scale;
  }
#pragma unroll
  for (int i = 0; i < G_IMG; ++i)
    outp[(size_t)(img0 + i) * 32 + u] = v[i];
}

// ================= Kernel 2: cortical columns + classifier (MFMA) =================
__global__ __launch_bounds__(256) void mnist_cols(
    const float* __restrict__ sensW, const float* __restrict__ tdW,
    const float* __restrict__ Wff,  const float* __restrict__ Wfb,
    const float* __restrict__ Wvel, const float* __restrict__ Wc1,
    const float* __restrict__ bc1,  const float* __restrict__ Wc2,
    const float* __restrict__ bc2,  float* __restrict__ out) {
  __shared__ float scr_all[4][16 * SCRW];    // 33 KB: per-wave transpose scratch

  const int tid = threadIdx.x;
  const int wv = tid >> 6, l = tid & 63;
  const int g = l >> 4, c0 = l & 15, c1 = c0 + 16;
  float* scr = scr_all[wv];
  const int s0 = blockIdx.x * 64 + wv * 16;

  // ---- sens/td for this wave's 16 samples (coalesced 16-lane rows) ----
  float sens[4][2], td[4][2];
#pragma unroll
  for (int r = 0; r < 4; ++r) {
    const int row = s0 + g * 4 + r;
    sens[r][0] = sensW[row * 32 + c0];
    sens[r][1] = sensW[row * 32 + c1];
    td[r][0]   = tdW[row * 32 + c0];
    td[r][1]   = tdW[row * 32 + c1];
  }

  // ---- weight fragments (hi+lo) ----
  f16x8 bfbh0, bfbl0, bfbh1, bfbl1, bffh0, bffl0, bffh1, bffl1;
  splitP(Wfb + c0 * 32 + g * 8, bfbh0, bfbl0);
  splitP(Wfb + c1 * 32 + g * 8, bfbh1, bfbl1);
  splitP(Wff + c0 * 32 + g * 8, bffh0, bffl0);
  splitP(Wff + c1 * 32 + g * 8, bffh1, bffl1);
  f16x8 afbh0, afbl0, afbh1, afbl1;
  splitS(Wfb + g * 256 + c0,      32, afbh0, afbl0);   // A-frags of Wfb^T, m-block 0
  splitS(Wfb + g * 256 + c0 + 16, 32, afbh1, afbl1);   // m-block 1
  const float wva0 = Wvel[c0 * 2], wva1 = Wvel[c0 * 2 + 1];
  const float wvb0 = Wvel[c1 * 2], wvb1 = Wvel[c1 * 2 + 1];

  // ---- M = Wfb^T @ Wff^T (f32-accurate 3-term hi/lo MFMA) ----
  const f32x4 zero = {0.f, 0.f, 0.f, 0.f};
  f32x4 m00 = mfma16(afbh0, bffl0, mfma16(afbl0, bffh0, mfma16(afbh0, bffh0, zero)));
  f32x4 m01 = mfma16(afbh0, bffl1, mfma16(afbl0, bffh1, mfma16(afbh0, bffh1, zero)));
  f32x4 m10 = mfma16(afbh1, bffl0, mfma16(afbl1, bffh0, mfma16(afbh1, bffh0, zero)));
  f32x4 m11 = mfma16(afbh1, bffl1, mfma16(afbl1, bffh1, mfma16(afbh1, bffh1, zero)));
#pragma unroll
  for (int r = 0; r < 4; ++r) {
    scr[(g * 4 + r) * 32 + c0]           = m00[r];
    scr[(g * 4 + r) * 32 + c0 + 16]      = m01[r];
    scr[(16 + g * 4 + r) * 32 + c0]      = m10[r];
    scr[(16 + g * 4 + r) * 32 + c0 + 16] = m11[r];
  }
  f16x8 mbh0, mbl0, mbh1, mbl1;   // B-frags of M
  splitS(scr + g * 256 + c0,      32, mbh0, mbl0);
  splitS(scr + g * 256 + c0 + 16, 32, mbh1, mbl1);

  f16x8 ahi, alo;
  // ---- y_fb = relu(td @ Wfb^T) ----
#pragma unroll
  for (int r = 0; r < 4; ++r) {
    int row = (g * 4 + r) * SCRW;
    scr[row + c0] = td[r][0];
    scr[row + c1] = td[r][1];
  }
  splitP(scr + c0 * SCRW + g * 8, ahi, alo);
  f32x4 f0 = mfma16(ahi, bfbl0, mfma16(alo, bfbh0, mfma16(ahi, bfbh0, zero)));
  f32x4 f1 = mfma16(ahi, bfbl1, mfma16(alo, bfbh1, mfma16(ahi, bfbh1, zero)));
  float yfb[4][2];
#pragma unroll
  for (int r = 0; r < 4; ++r) { yfb[r][0] = fmaxf(f0[r], 0.f); yfb[r][1] = fmaxf(f1[r], 0.f); }

  // ---- s_ff = sens @ Wff^T ----
#pragma unroll
  for (int r = 0; r < 4; ++r) {
    int row = (g * 4 + r) * SCRW;
    scr[row + c0] = sens[r][0];
    scr[row + c1] = sens[r][1];
  }
  splitP(scr + c0 * SCRW + g * 8, ahi, alo);
  f32x4 sff0 = mfma16(ahi, bffl0, mfma16(alo, bffh0, mfma16(ahi, bffh0, zero)));
  f32x4 sff1 = mfma16(ahi, bffl1, mfma16(alo, bffh1, mfma16(ahi, bffh1, zero)));

  // ---- merged recurrence: y_ff = relu(s_ff - r6@M); r6 += 0.1(-r6+y_ff+y_fb+vin) ----
  float r6[4][2] = {}, d[4][2] = {}, yff[4][2] = {};
  const float VX[3] = {0.2f, 0.0f, 0.15f};
  const float VY[3] = {0.0f, 0.2f, 0.15f};
#pragma unroll
  for (int v = 0; v < 3; ++v) {
    float vin[2];
    vin[0] = wva0 * VX[v] + wva1 * VY[v];
    vin[1] = wvb0 * VX[v] + wvb1 * VY[v];
#pragma unroll
    for (int st = 0; st < 3; ++st) {
#pragma unroll
      for (int r = 0; r < 4; ++r) {
        int row = (g * 4 + r) * SCRW;
        scr[row + c0] = -r6[r][0];
        scr[row + c1] = -r6[r][1];
      }
      splitP(scr + c0 * SCRW + g * 8, ahi, alo);
      f32x4 y0 = mfma16(ahi, mbl0, mfma16(alo, mbh0, mfma16(ahi, mbh0, sff0)));
      f32x4 y1 = mfma16(ahi, mbl1, mfma16(alo, mbh1, mfma16(ahi, mbh1, sff1)));
      if (v == 2 && st == 2) {
        f32x4 t0 = mfma16(ahi, bfbl0, mfma16(alo, bfbh0, mfma16(ahi, bfbh0, zero)));
        f32x4 t1 = mfma16(ahi, bfbl1, mfma16(alo, bfbh1, mfma16(ahi, bfbh1, zero)));
#pragma unroll
        for (int r = 0; r < 4; ++r) { d[r][0] = sens[r][0] + t0[r]; d[r][1] = sens[r][1] + t1[r]; }
      }
#pragma unroll
      for (int r = 0; r < 4; ++r) {
        yff[r][0] = fmaxf(y0[r], 0.f);
        yff[r][1] = fmaxf(y1[r], 0.f);
        r6[r][0] += 0.1f * (yff[r][0] - r6[r][0] + yfb[r][0] + vin[0]);
        r6[r][1] += 0.1f * (yff[r][1] - r6[r][1] + yfb[r][1] + vin[1]);
      }
    }
  }

  // ---- feature = [y_ff | y_fb | r6 | |d|] ----
#pragma unroll
  for (int r = 0; r < 4; ++r) {
    int row = (g * 4 + r) * SCRW;
    scr[row +      c0] = yff[r][0];        scr[row +      c1] = yff[r][1];
    scr[row + 32 + c0] = yfb[r][0];        scr[row + 32 + c1] = yfb[r][1];
    scr[row + 64 + c0] = r6[r][0];         scr[row + 64 + c1] = r6[r][1];
    scr[row + 96 + c0] = fabsf(d[r][0]);   scr[row + 96 + c1] = fabsf(d[r][1]);
  }
  f32x4 acc0 = zero, acc1 = zero, acc2 = zero, acc3 = zero;
#pragma unroll
  for (int kb = 0; kb < 4; ++kb) {
    f16x8 fhi, flo;
    splitP(scr + c0 * SCRW + kb * 32 + g * 8, fhi, flo);
    const int ko = kb * 32 + g * 8;
    f16x8 b0 = bfrag8(Wc1 + (size_t)(c0)      * 128 + ko);
    f16x8 b1 = bfrag8(Wc1 + (size_t)(16 + c0) * 128 + ko);
    f16x8 b2 = bfrag8(Wc1 + (size_t)(32 + c0) * 128 + ko);
    f16x8 b3 = bfrag8(Wc1 + (size_t)(48 + c0) * 128 + ko);
    acc0 = mfma16(flo, b0, mfma16(fhi, b0, acc0));
    acc1 = mfma16(flo, b1, mfma16(fhi, b1, acc1));
    acc2 = mfma16(flo, b2, mfma16(fhi, b2, acc2));
    acc3 = mfma16(flo, b3, mfma16(fhi, b3, acc3));
  }
  float h[4][4];
  const float B0 = bc1[c0], B1 = bc1[16 + c0], B2 = bc1[32 + c0], B3 = bc1[48 + c0];
#pragma unroll
  for (int r = 0; r < 4; ++r) {
    float x0 = acc0[r] + B0, x1 = acc1[r] + B1, x2 = acc2[r] + B2, x3 = acc3[r] + B3;
    h[r][0] = 0.5f * x0 * (1.0f + erff(x0 * 0.70710678118654752f));
    h[r][1] = 0.5f * x1 * (1.0f + erff(x1 * 0.70710678118654752f));
    h[r][2] = 0.5f * x2 * (1.0f + erff(x2 * 0.70710678118654752f));
    h[r][3] = 0.5f * x3 * (1.0f + erff(x3 * 0.70710678118654752f));
  }

  // ---- logits = h @ Wc2^T + bc2 ----
#pragma unroll
  for (int r = 0; r < 4; ++r) {
    int row = (g * 4 + r) * SCRW;
#pragma unroll
    for (int nb = 0; nb < 4; ++nb) scr[row + nb * 16 + c0] = h[r][nb];
  }
  f32x4 accL = zero;
#pragma unroll
  for (int kb = 0; kb < 2; ++kb) {
    f16x8 hhi, hlo;
    splitP(scr + c0 * SCRW + kb * 32 + g * 8, hhi, hlo);
    f16x8 b;
    if (c0 < 10) {
      b = bfrag8(Wc2 + (size_t)c0 * 64 + kb * 32 + g * 8);
    } else {
#pragma unroll
      for (int j = 0; j < 8; ++j) b[j] = (_Float16)0.f;
    }
    accL = mfma16(hlo, b, mfma16(hhi, b, accL));
  }
  if (c0 < 10) {
    const float bb = bc2[c0];
#pragma unroll
    for (int r = 0; r < 4; ++r)
      out[(size_t)(s0 + g * 4 + r) * 10 + c0] = accL[r] + bb;
  }
}

extern "C" void kernel_launch(void* const* d_in, const int* in_sizes, int n_in,
                              void* d_out, int out_size, void* d_ws, size_t ws_size,
                              hipStream_t stream) {
  const float* img  = (const float*)d_in[0];
  const float* Wff  = (const float*)d_in[1];
  const float* Wfb  = (const float*)d_in[2];
  const float* Wvel = (const float*)d_in[3];
  const float* Wc1  = (const float*)d_in[4];
  const float* bc1  = (const float*)d_in[5];
  const float* Wc2  = (const float*)d_in[6];
  const float* bc2  = (const float*)d_in[7];
  float* out = (float*)d_out;
  const int B = in_sizes[0] / 784;     // 16384

  float* sensW = (float*)d_ws;         // [B][32]
  float* tdW   = sensW + (size_t)B * 32;

  const int grid1 = B / (4 * G_IMG);   // 512 blocks, 2048 waves
  hipLaunchKernelGGL(interp_k, dim3(grid1), dim3(256), 0, stream, img, sensW, tdW);

  const int grid2 = B / 64;            // 256 blocks
  hipLaunchKernelGGL(mnist_cols, dim3(grid2), dim3(256), 0, stream,
                     sensW, tdW, Wff, Wfb, Wvel, Wc1, bc1, Wc2, bc2, out);
}

// Round 4
// 25.274 us; speedup vs baseline: 1.0622x; 1.0622x over previous
//
#include <hip/hip_runtime.h>
#include <math.h>

typedef _Float16 f16x8 __attribute__((ext_vector_type(8)));
typedef float    f32x4 __attribute__((ext_vector_type(4)));

#define SCRW 132
#define MLDW 33

typedef __attribute__((address_space(3))) void lds_void;
typedef const __attribute__((address_space(1))) void glb_void;

__device__ __forceinline__ f32x4 mfma16(f16x8 a, f16x8 b, f32x4 c) {
  return __builtin_amdgcn_mfma_f32_16x16x32_f16(a, b, c, 0, 0, 0);
}

// 8 f32 (register array) -> hi/lo f16x8 (hi+lo ~= exact)
__device__ __forceinline__ void pack8(const float* v, f16x8& hi, f16x8& lo) {
#pragma unroll
  for (int j = 0; j < 8; ++j) {
    _Float16 h = (_Float16)v[j];
    hi[j] = h;
    lo[j] = (_Float16)(v[j] - (float)h);
  }
}

// 8 contiguous f32 -> single-f16 B fragment (classifier weights)
__device__ __forceinline__ f16x8 bfrag8(const float* p) {
  const f32x4* q = (const f32x4*)p;
  f32x4 w0 = q[0], w1 = q[1];
  f16x8 b;
#pragma unroll
  for (int j = 0; j < 4; ++j) { b[j] = (_Float16)w0[j]; b[j + 4] = (_Float16)w1[j]; }
  return b;
}

// 8 contiguous f32 -> hi/lo (classifier feature frags)
__device__ __forceinline__ void splitP(const float* p, f16x8& hi, f16x8& lo) {
  const f32x4* q = (const f32x4*)p;
  f32x4 a0 = q[0], a1 = q[1];
#pragma unroll
  for (int j = 0; j < 4; ++j) {
    _Float16 h0 = (_Float16)a0[j], h1 = (_Float16)a1[j];
    hi[j] = h0; hi[j + 4] = h1;
    lo[j]     = (_Float16)(a0[j] - (float)h0);
    lo[j + 4] = (_Float16)(a1[j] - (float)h1);
  }
}

// stream one 4-image chunk (12544 B) global -> LDS, coalesced
__device__ __forceinline__ void load_chunk(const float* gsrc, float* lbase, int l) {
#pragma unroll
  for (int i = 0; i < 12; ++i)
    __builtin_amdgcn_global_load_lds((glb_void*)(gsrc + i * 256 + l * 4),
                                     (lds_void*)(lbase + i * 256), 16, 0, 0);
  __builtin_amdgcn_global_load_lds((glb_void*)(gsrc + 3072 + l),
                                   (lds_void*)(lbase + 3072), 4, 0, 0);
}

// Lane roles (g = l>>4, c = l&15):
//   Transposed state quads: lane holds, for SAMPLE c, units {g*4+e} (q0) and {16+g*4+e} (q1).
//   B-frag of state: lane supplies state[sample c][unit g*8+j], j=0..7.
//   A-frags (row = c): out-unit (or hidden) index c within 16-block.
__global__ __launch_bounds__(256) void mnist_fused(
    const float* __restrict__ img,  const float* __restrict__ Wff,
    const float* __restrict__ Wfb,  const float* __restrict__ Wvel,
    const float* __restrict__ Wc1,  const float* __restrict__ bc1,
    const float* __restrict__ Wc2,  const float* __restrict__ bc2,
    float* __restrict__ out) {
  __shared__ float img_lds[4][784 * 4];     // 50 KB: per-wave 4-image chunk
  __shared__ float scr_all[4][16 * SCRW];   // 33 KB: per-wave scratch (M, then classifier)

  const int tid = threadIdx.x;
  const int wv = tid >> 6, l = tid & 63;
  const int g = l >> 4, c = l & 15;
  float* scr  = scr_all[wv];
  float* Mlds = scr;                        // 32*33=1056 floats <= 2112, M is dead before classifier
  float* ibuf = img_lds[wv];
  const int s0 = blockIdx.x * 64 + wv * 16;
  const f32x4 zero = {0.f, 0.f, 0.f, 0.f};

  // ---- raw weight loads FIRST (so compiler's weight-waits don't drain chunk DMA) ----
  f32x4 rff[4], rfb[4];
  rff[0] = *(const f32x4*)(Wff + c * 32 + g * 8);
  rff[1] = *(const f32x4*)(Wff + c * 32 + g * 8 + 4);
  rff[2] = *(const f32x4*)(Wff + (16 + c) * 32 + g * 8);
  rff[3] = *(const f32x4*)(Wff + (16 + c) * 32 + g * 8 + 4);
  rfb[0] = *(const f32x4*)(Wfb + c * 32 + g * 8);
  rfb[1] = *(const f32x4*)(Wfb + c * 32 + g * 8 + 4);
  rfb[2] = *(const f32x4*)(Wfb + (16 + c) * 32 + g * 8);
  rfb[3] = *(const f32x4*)(Wfb + (16 + c) * 32 + g * 8 + 4);
  float rT0[8], rT1[8];                     // Wfb^T A-frag rows (strided)
#pragma unroll
  for (int j = 0; j < 8; ++j) {
    rT0[j] = Wfb[(g * 8 + j) * 32 + c];
    rT1[j] = Wfb[(g * 8 + j) * 32 + 16 + c];
  }
  float2 wv0[4], wv1[4];
#pragma unroll
  for (int e = 0; e < 4; ++e) {
    wv0[e] = ((const float2*)Wvel)[g * 4 + e];
    wv1[e] = ((const float2*)Wvel)[16 + g * 4 + e];
  }
  __builtin_amdgcn_sched_barrier(0);

  // ---- start streaming chunk 0 ----
  load_chunk(img + (size_t)s0 * 784, ibuf, l);

  // ---- tap index math (VALU, overlaps DMA) ----
  int loB[8], taB[8], tbB[8], loQ[8];
  float wB[8], wQ[8];
#pragma unroll
  for (int j = 0; j < 8; ++j) {
    int u = g * 8 + j;
    float pos = 24.5f * (float)u + 11.75f;
    loB[j] = (int)pos; wB[j] = pos - (float)loB[j];
    int lt = loB[j];
    taB[j] = (lt % 28) * 28 + lt / 28;
    lt += 1;
    tbB[j] = (lt % 28) * 28 + lt / 28;
  }
#pragma unroll
  for (int e2 = 0; e2 < 8; ++e2) {
    int u = (e2 >> 2) * 16 + g * 4 + (e2 & 3);
    float pos = 24.5f * (float)u + 11.75f;
    loQ[e2] = (int)pos; wQ[e2] = pos - (float)loQ[e2];
  }

  // ---- convert weight frags ----
  f16x8 bffh0, bffl0, bffh1, bffl1, bfbh0, bfbl0, bfbh1, bfbl1;
  {
    float t[8];
#pragma unroll
    for (int j = 0; j < 4; ++j) { t[j] = rff[0][j]; t[4 + j] = rff[1][j]; }
    pack8(t, bffh0, bffl0);
#pragma unroll
    for (int j = 0; j < 4; ++j) { t[j] = rff[2][j]; t[4 + j] = rff[3][j]; }
    pack8(t, bffh1, bffl1);
#pragma unroll
    for (int j = 0; j < 4; ++j) { t[j] = rfb[0][j]; t[4 + j] = rfb[1][j]; }
    pack8(t, bfbh0, bfbl0);
#pragma unroll
    for (int j = 0; j < 4; ++j) { t[j] = rfb[2][j]; t[4 + j] = rfb[3][j]; }
    pack8(t, bfbh1, bfbl1);
  }
  f16x8 aT0h, aT0l, aT1h, aT1l;
  pack8(rT0, aT0h, aT0l);
  pack8(rT1, aT1h, aT1l);

  // ---- M = Wfb^T @ Wff^T (3-term hi/lo), stash in LDS, pull out A-frags of -M^T ----
  f32x4 m00 = mfma16(aT0h, bffl0, mfma16(aT0l, bffh0, mfma16(aT0h, bffh0, zero)));
  f32x4 m01 = mfma16(aT0h, bffl1, mfma16(aT0l, bffh1, mfma16(aT0h, bffh1, zero)));
  f32x4 m10 = mfma16(aT1h, bffl0, mfma16(aT1l, bffh0, mfma16(aT1h, bffh0, zero)));
  f32x4 m11 = mfma16(aT1h, bffl1, mfma16(aT1l, bffh1, mfma16(aT1h, bffh1, zero)));
#pragma unroll
  for (int r = 0; r < 4; ++r) {
    Mlds[(g * 4 + r) * MLDW + c]            = m00[r];
    Mlds[(g * 4 + r) * MLDW + 16 + c]       = m01[r];
    Mlds[(16 + g * 4 + r) * MLDW + c]       = m10[r];
    Mlds[(16 + g * 4 + r) * MLDW + 16 + c]  = m11[r];
  }
  f16x8 nMt0h, nMt0l, nMt1h, nMt1l;
  {
    float m[8];
#pragma unroll
    for (int j = 0; j < 8; ++j) m[j] = -Mlds[(g * 8 + j) * MLDW + c];
    pack8(m, nMt0h, nMt0l);
#pragma unroll
    for (int j = 0; j < 8; ++j) m[j] = -Mlds[(g * 8 + j) * MLDW + 16 + c];
    pack8(m, nMt1h, nMt1l);
  }

  // ---- stream chunks; each lane extracts its own taps during its chunk ----
  float sB[8] = {}, tB[8] = {}, sQ[8] = {};
#pragma unroll
  for (int ch = 0; ch < 4; ++ch) {
    asm volatile("s_waitcnt vmcnt(0)" ::: "memory");
    __builtin_amdgcn_sched_barrier(0);
    if ((c >> 2) == ch) {
      const float* base = ibuf + (c & 3) * 784;
#pragma unroll
      for (int j = 0; j < 8; ++j) {
        float a = base[loB[j]], b2 = base[loB[j] + 1];
        sB[j] = (a + (b2 - a) * wB[j]) * 80.0f;
      }
#pragma unroll
      for (int j = 0; j < 8; ++j) {
        float a = base[taB[j]], b2 = base[tbB[j]];
        tB[j] = (a + (b2 - a) * wB[j]) * 40.0f;
      }
#pragma unroll
      for (int e2 = 0; e2 < 8; ++e2) {
        float a = base[loQ[e2]], b2 = base[loQ[e2] + 1];
        sQ[e2] = (a + (b2 - a) * wQ[e2]) * 80.0f;
      }
    }
    if (ch < 3) load_chunk(img + (size_t)(s0 + (ch + 1) * 4) * 784, ibuf, l);
  }

  // ---- B-frags of Sens^T / Td^T; sens quads ----
  f16x8 snh, snl, tdh, tdl;
  pack8(sB, snh, snl);
  pack8(tB, tdh, tdl);
  f32x4 SN0 = {sQ[0], sQ[1], sQ[2], sQ[3]};
  f32x4 SN1 = {sQ[4], sQ[5], sQ[6], sQ[7]};

  // ---- SF = (Wff·Sens^T) quads; YFB = relu(Wfb·Td^T) quads ----
  f32x4 SF0 = mfma16(bffh0, snh, zero);
  SF0 += mfma16(bffl0, snh, mfma16(bffh0, snl, zero));
  f32x4 SF1 = mfma16(bffh1, snh, zero);
  SF1 += mfma16(bffl1, snh, mfma16(bffh1, snl, zero));
  f32x4 YFB0 = mfma16(bfbh0, tdh, zero);
  YFB0 += mfma16(bfbl0, tdh, mfma16(bfbh0, tdl, zero));
  f32x4 YFB1 = mfma16(bfbh1, tdh, zero);
  YFB1 += mfma16(bfbl1, tdh, mfma16(bfbh1, tdl, zero));
#pragma unroll
  for (int e = 0; e < 4; ++e) {
    YFB0[e] = fmaxf(YFB0[e], 0.f);
    YFB1[e] = fmaxf(YFB1[e], 0.f);
  }

  // ---- register recurrence: Y^T = SF - M^T·R6^T ; update in C-quad layout ----
  const int addrA = ((2 * (g & 1)) * 16 + c) * 4;   // bpermute byte addr
  const int addrB = addrA + 64;
  const bool hiG = (g >= 2);
  f32x4 r6q0 = zero, r6q1 = zero;
  f32x4 yf0 = zero, yf1 = zero, dq0 = zero, dq1 = zero;
  const float VX[3] = {0.2f, 0.0f, 0.15f};
  const float VY[3] = {0.0f, 0.2f, 0.15f};
#pragma unroll
  for (int v = 0; v < 3; ++v) {
    f32x4 vq0, vq1;
#pragma unroll
    for (int e = 0; e < 4; ++e) {
      vq0[e] = wv0[e].x * VX[v] + wv0[e].y * VY[v];
      vq1[e] = wv1[e].x * VX[v] + wv1[e].y * VY[v];
    }
#pragma unroll
    for (int st = 0; st < 3; ++st) {
      // exchange C-quads -> B-frag order (16 independent bpermutes)
      float t[8];
#pragma unroll
      for (int e = 0; e < 4; ++e) {
        int q0i = __float_as_int(r6q0[e]), q1i = __float_as_int(r6q1[e]);
        float a0 = __int_as_float(__builtin_amdgcn_ds_bpermute(addrA, q0i));
        float a1 = __int_as_float(__builtin_amdgcn_ds_bpermute(addrA, q1i));
        float b0 = __int_as_float(__builtin_amdgcn_ds_bpermute(addrB, q0i));
        float b1 = __int_as_float(__builtin_amdgcn_ds_bpermute(addrB, q1i));
        t[e]     = hiG ? a1 : a0;
        t[4 + e] = hiG ? b1 : b0;
      }
      f16x8 bh, bl;
      pack8(t, bh, bl);
      // y = SF - M^T r6  (two parallel MFMA chains, depth 2, then add)
      f32x4 y0 = mfma16(nMt0h, bh, SF0);
      y0 += mfma16(nMt0l, bh, mfma16(nMt0h, bl, zero));
      f32x4 y1 = mfma16(nMt1h, bh, SF1);
      y1 += mfma16(nMt1l, bh, mfma16(nMt1h, bl, zero));
      if (v == 2 && st == 2) {
        // d = sens - r6·Wfb^T (transposed: SN - Wfb·R6^T), reusing this step's B-frag
        f32x4 p0 = mfma16(bfbh0, bh, zero);
        p0 += mfma16(bfbl0, bh, mfma16(bfbh0, bl, zero));
        f32x4 p1 = mfma16(bfbh1, bh, zero);
        p1 += mfma16(bfbl1, bh, mfma16(bfbh1, bl, zero));
#pragma unroll
        for (int e = 0; e < 4; ++e) { dq0[e] = SN0[e] - p0[e]; dq1[e] = SN1[e] - p1[e]; }
      }
#pragma unroll
      for (int e = 0; e < 4; ++e) {
        yf0[e] = fmaxf(y0[e], 0.f);
        yf1[e] = fmaxf(y1[e], 0.f);
        r6q0[e] += 0.1f * (yf0[e] - r6q0[e] + YFB0[e] + vq0[e]);
        r6q1[e] += 0.1f * (yf1[e] - r6q1[e] + YFB1[e] + vq1[e]);
      }
    }
  }

  // ---- feature = [y_ff | y_fb | r6 | |d|] -> scr rows = samples ----
  {
    const int b0 = c * SCRW;
#pragma unroll
    for (int e = 0; e < 4; ++e) {
      scr[b0 +       g * 4 + e] = yf0[e];
      scr[b0 + 16  + g * 4 + e] = yf1[e];
      scr[b0 + 32  + g * 4 + e] = YFB0[e];
      scr[b0 + 48  + g * 4 + e] = YFB1[e];
      scr[b0 + 64  + g * 4 + e] = r6q0[e];
      scr[b0 + 80  + g * 4 + e] = r6q1[e];
      scr[b0 + 96  + g * 4 + e] = fabsf(dq0[e]);
      scr[b0 + 112 + g * 4 + e] = fabsf(dq1[e]);
    }
  }

  // ---- classifier (verified round-1 code) ----
  f32x4 acc0 = zero, acc1 = zero, acc2 = zero, acc3 = zero;
#pragma unroll
  for (int kb = 0; kb < 4; ++kb) {
    f16x8 fhi, flo;
    splitP(scr + c * SCRW + kb * 32 + g * 8, fhi, flo);
    const int ko = kb * 32 + g * 8;
    f16x8 b0 = bfrag8(Wc1 + (size_t)(c)      * 128 + ko);
    f16x8 b1 = bfrag8(Wc1 + (size_t)(16 + c) * 128 + ko);
    f16x8 b2 = bfrag8(Wc1 + (size_t)(32 + c) * 128 + ko);
    f16x8 b3 = bfrag8(Wc1 + (size_t)(48 + c) * 128 + ko);
    acc0 = mfma16(flo, b0, mfma16(fhi, b0, acc0));
    acc1 = mfma16(flo, b1, mfma16(fhi, b1, acc1));
    acc2 = mfma16(flo, b2, mfma16(fhi, b2, acc2));
    acc3 = mfma16(flo, b3, mfma16(fhi, b3, acc3));
  }
  float h[4][4];
  const float B0 = bc1[c], B1 = bc1[16 + c], B2 = bc1[32 + c], B3 = bc1[48 + c];
#pragma unroll
  for (int r = 0; r < 4; ++r) {
    float x0 = acc0[r] + B0, x1 = acc1[r] + B1, x2 = acc2[r] + B2, x3 = acc3[r] + B3;
    h[r][0] = 0.5f * x0 * (1.0f + erff(x0 * 0.70710678118654752f));
    h[r][1] = 0.5f * x1 * (1.0f + erff(x1 * 0.70710678118654752f));
    h[r][2] = 0.5f * x2 * (1.0f + erff(x2 * 0.70710678118654752f));
    h[r][3] = 0.5f * x3 * (1.0f + erff(x3 * 0.70710678118654752f));
  }
#pragma unroll
  for (int r = 0; r < 4; ++r) {
    int row = (g * 4 + r) * SCRW;
#pragma unroll
    for (int nb = 0; nb < 4; ++nb) scr[row + nb * 16 + c] = h[r][nb];
  }
  f32x4 accL = zero;
#pragma unroll
  for (int kb = 0; kb < 2; ++kb) {
    f16x8 hhi, hlo;
    splitP(scr + c * SCRW + kb * 32 + g * 8, hhi, hlo);
    f16x8 b;
    if (c < 10) {
      b = bfrag8(Wc2 + (size_t)c * 64 + kb * 32 + g * 8);
    } else {
#pragma unroll
      for (int j = 0; j < 8; ++j) b[j] = (_Float16)0.f;
    }
    accL = mfma16(hlo, b, mfma16(hhi, b, accL));
  }
  if (c < 10) {
    const float bb = bc2[c];
#pragma unroll
    for (int r = 0; r < 4; ++r)
      out[(size_t)(s0 + g * 4 + r) * 10 + c] = accL[r] + bb;
  }
}

extern "C" void kernel_launch(void* const* d_in, const int* in_sizes, int n_in,
                              void* d_out, int out_size, void* d_ws, size_t ws_size,
                              hipStream_t stream) {
  const float* img  = (const float*)d_in[0];
  const float* Wff  = (const float*)d_in[1];
  const float* Wfb  = (const float*)d_in[2];
  const float* Wvel = (const float*)d_in[3];
  const float* Wc1  = (const float*)d_in[4];
  const float* bc1  = (const float*)d_in[5];
  const float* Wc2  = (const float*)d_in[6];
  const float* bc2  = (const float*)d_in[7];
  float* out = (float*)d_out;
  const int B = in_sizes[0] / 784;     // 16384
  const int grid = B / 64;             // 64 samples / block (4 waves x 16)
  hipLaunchKernelGGL(mnist_fused, dim3(grid), dim3(256), 0, stream,
                     img, Wff, Wfb, Wvel, Wc1, bc1, Wc2, bc2, out);
}